// Round 20
// baseline (163.901 us; speedup 1.0000x reference)
//
#include <hip/hip_runtime.h>

typedef unsigned short u16;
typedef unsigned int   u32;
typedef __attribute__((ext_vector_type(8)))  short short8;   // 8 x bf16 (raw bits)
typedef __attribute__((ext_vector_type(4)))  float f32x4;
typedef __attribute__((ext_vector_type(16))) float f32x16;

#define DI __device__ __forceinline__

DI u16 f2bf(float f){
  u32 u = __builtin_bit_cast(u32, f);
  u += 0x7fffu + ((u >> 16) & 1u);          // round-to-nearest-even
  return (u16)(u >> 16);
}

DI void gl_lds16(const void* g, void* l){
  __builtin_amdgcn_global_load_lds((const __attribute__((address_space(1))) void*)g,
                                   (__attribute__((address_space(3))) void*)l, 16, 0, 0);
}

DI f32x4 mfma16(short8 a, short8 b, f32x4 c){
  return __builtin_amdgcn_mfma_f32_16x16x32_bf16(a, b, c, 0, 0, 0);
}
DI f32x16 mfma32(short8 a, short8 b, f32x16 c){
  return __builtin_amdgcn_mfma_f32_32x32x16_bf16(a, b, c, 0, 0, 0);
}
DI f32x16 z16(){
  f32x16 v;
  #pragma unroll
  for (int i=0;i<16;i++) v[i]=0.f;
  return v;
}

union U8 { u32 u[4]; short8 s; };

// ---------------- workspace layout (bytes) ----------------
#define OFF_WBF   0u
#define OFF_STATS (512u<<10)
#define OFF_Q     ((1u<<20) + (8u<<20))
#define OFF_K     ((1u<<20) + (16u<<20))
#define OFF_VT    ((1u<<20) + (24u<<20))
#define OFF_H2T   OFF_Q                     // alias: q dead before k_combine writes h2t
#define OFF_PART  ((1u<<20) + (32u<<20))    // 16 combos x (4096,256) bf16 = 32 MB
#define OFF_ML    ((1u<<20) + (96u<<20))    // 16 combos x 4096 float2 = 512 KB

// ------- kernel 0+1 merged: weight bf16 prep (blocks 0..255) + gn stats (256..767) -------
__global__ void k_prepstats(const float* wq, const float* wk, const float* wv, const float* wo,
                            u16* wbf, const float* x, float2* stats){
  const int bid = blockIdx.x;
  if (bid < 256){
    const int wi = bid >> 6;                  // 0..3
    const float* src = (wi==0)?wq:(wi==1)?wk:(wi==2)?wv:wo;
    u16* d = wbf + wi*65536;
    int i = ((bid&63)*256 + threadIdx.x)*4;
    float4 v = *(const float4*)(src + i);
    u32 lo = (u32)f2bf(v.x) | ((u32)f2bf(v.y)<<16);
    u32 hi = (u32)f2bf(v.z) | ((u32)f2bf(v.w)<<16);
    *(uint2*)(d + i) = make_uint2(lo, hi);
    return;
  }
  const int bg = bid - 256;                    // 0..511: b*128 + g
  const float* p = x + (size_t)bg*8192;
  float s = 0.f, ss = 0.f;
  #pragma unroll
  for (int i=0;i<8;i++){
    float4 v = *(const float4*)(p + threadIdx.x*4 + i*1024);
    s  += v.x+v.y+v.z+v.w;
    ss += v.x*v.x + v.y*v.y + v.z*v.z + v.w*v.w;
  }
  #pragma unroll
  for (int off=1; off<64; off<<=1){ s += __shfl_xor(s, off, 64); ss += __shfl_xor(ss, off, 64); }
  __shared__ float as[4], aq[4];
  int w = threadIdx.x>>6;
  if ((threadIdx.x&63)==0){ as[w]=s; aq[w]=ss; }
  __syncthreads();
  if (threadIdx.x==0){
    s = as[0]+as[1]+as[2]+as[3]; ss = aq[0]+aq[1]+aq[2]+aq[3];
    float mu = s * (1.f/8192.f);
    float var = ss * (1.f/8192.f) - mu*mu;
    stats[bg] = make_float2(mu, rsqrtf(var + 1e-5f));
  }
}

// ---------------- kernel 3: fused GroupNorm + QKV projections ----------------
// grid 256 x 256 thr: block = 64 tokens. Phase 0 normalizes x directly into
// lds_a in GEMM-A layout (validated round 17).
__global__ __launch_bounds__(256,2) void k_qkv(const float* x, const float* gw,
    const float* gb, const float2* stats, const u16* wbf,
    const float* bq, const float* bk, const float* bv,
    u16* qo, u16* ko, u16* vt){
  __shared__ u16 lds_a[64*256];    // 32KB
  const int t = threadIdx.x, row0 = blockIdx.x*64;
  const int w = t>>6, l = t&63, lo = l&15, hi = l>>4;
  // ---- phase 0: normalize 64-token x tile straight into lds_a ----
  {
    const int b = row0>>12, n0 = row0&4095;
    const float* xb = x + (size_t)b*1048576;
    #pragma unroll
    for (int p=0;p<4;p++){
      int c = p*64 + (t>>2);
      float2 st = stats[b*128 + (c>>1)];
      float scl = st.y * gw[c];
      float off = gb[c] - st.x*scl;
      const float* src = xb + (size_t)c*4096 + n0 + (t&3)*16;
      #pragma unroll
      for (int u2=0;u2<4;u2++){
        float4 v = *(const float4*)(src + u2*4);
        float vv[4] = {v.x,v.y,v.z,v.w};
        #pragma unroll
        for (int j=0;j<4;j++){
          int n = (t&3)*16 + u2*4 + j;
          int addr = n*512 + ((c*2) ^ ((n&7)<<4));
          *(u16*)((char*)lds_a + addr) = f2bf(vv[j]*scl + off);
        }
      }
    }
    __syncthreads();
  }
  auto compute = [&](const u16* W, f32x4 acc[4][4]){
    #pragma unroll
    for (int i=0;i<4;i++)
      #pragma unroll
      for (int j=0;j<4;j++) acc[i][j] = (f32x4){0.f,0.f,0.f,0.f};
    const char* Wb = (const char*)W;
    #pragma unroll
    for (int dk=0; dk<4; dk++){
      #pragma unroll
      for (int s=0;s<2;s++){
        short8 af[4], bf[4];
        #pragma unroll
        for (int cf=0;cf<4;cf++){
          int col = w*64 + cf*16 + lo;
          bf[cf] = *(const short8*)(Wb + (size_t)col*512 + dk*128 + s*64 + hi*16);
        }
        #pragma unroll
        for (int rg=0;rg<4;rg++){
          int row = rg*16 + lo;
          af[rg] = *(const short8*)((const char*)lds_a + row*512 + ((dk*128 + s*64 + hi*16) ^ ((row&7)<<4)));
        }
        #pragma unroll
        for (int rg=0;rg<4;rg++)
          #pragma unroll
          for (int cf=0;cf<4;cf++)
            acc[rg][cf] = mfma16(af[rg], bf[cf], acc[rg][cf]);
      }
    }
  };
  f32x4 acc[4][4];
  compute(wbf, acc);
  #pragma unroll
  for (int rg=0;rg<4;rg++)
    #pragma unroll
    for (int cf=0;cf<4;cf++){
      int col = w*64 + cf*16 + lo;
      float bs = bq[col];
      #pragma unroll
      for (int r=0;r<4;r++){
        int grow = row0 + rg*16 + hi*4 + r;
        qo[(size_t)grow*256 + col] = f2bf((acc[rg][cf][r] + bs)*0.09016844f);
      }
    }
  compute(wbf + 65536, acc);
  #pragma unroll
  for (int rg=0;rg<4;rg++)
    #pragma unroll
    for (int cf=0;cf<4;cf++){
      int col = w*64 + cf*16 + lo;
      float bs = bk[col];
      #pragma unroll
      for (int r=0;r<4;r++){
        int grow = row0 + rg*16 + hi*4 + r;
        ko[(size_t)grow*256 + col] = f2bf(acc[rg][cf][r] + bs);
      }
    }
  compute(wbf + 2*65536, acc);
  __syncthreads();
  #pragma unroll
  for (int rg=0;rg<4;rg++)
    #pragma unroll
    for (int cf=0;cf<4;cf++){
      int col = w*64 + cf*16 + lo;
      float bs = bv[col];
      ushort4 pk;
      pk.x = f2bf(acc[rg][cf][0]+bs); pk.y = f2bf(acc[rg][cf][1]+bs);
      pk.z = f2bf(acc[rg][cf][2]+bs); pk.w = f2bf(acc[rg][cf][3]+bs);
      int rl = rg*16 + hi*4;
      int addr = col*128 + ((rl*2) ^ ((col&7)<<4));     // lds_a reused: [256 c][64 rows]
      *(ushort4*)((char*)lds_a + addr) = pk;
    }
  __syncthreads();
  {
    int b = row0 >> 12, nb = row0 & 4095;
    #pragma unroll
    for (int p=0;p<8;p++){
      int c = p*32 + (t>>3), i = t&7;
      uint4 vd = *(const uint4*)((const char*)lds_a + c*128 + ((i*16) ^ ((c&7)<<4)));
      *(uint4*)((char*)vt + ((size_t)(b*256 + c)*4096 + nb)*2 + i*16) = vd;
    }
  }
}

// ---------------- kernel 5: output projection + residual ----------------
__global__ __launch_bounds__(256,2) void k_out(const u16* h2t, const u16* wo,
    const float* bo, const float* x, float* out){
  __shared__ u16 lds_a[64*256];
  const int t = threadIdx.x, row0 = blockIdx.x*64;
  const int w = t>>6, l = t&63, lo = l&15, hi = l>>4;
  {
    const char* Ab = (const char*)h2t + (size_t)row0*512;
    #pragma unroll
    for (int i=0;i<8;i++){
      int row = w*16 + i*2 + (l>>5);
      gl_lds16(Ab + row*512 + (((l&31)*16) ^ ((row&7)<<4)), lds_a + w*4096 + i*512);
    }
    __syncthreads();
  }
  f32x4 acc[4][4];
  #pragma unroll
  for (int i=0;i<4;i++)
    #pragma unroll
    for (int j=0;j<4;j++) acc[i][j] = (f32x4){0.f,0.f,0.f,0.f};
  const char* Wb = (const char*)wo;
  #pragma unroll
  for (int dk=0; dk<4; dk++){
    #pragma unroll
    for (int s=0;s<2;s++){
      short8 af[4], bf[4];
      #pragma unroll
      for (int cf=0;cf<4;cf++){
        int col = w*64 + cf*16 + lo;
        bf[cf] = *(const short8*)(Wb + (size_t)col*512 + dk*128 + s*64 + hi*16);
      }
      #pragma unroll
      for (int rg=0;rg<4;rg++){
        int row = rg*16 + lo;
        af[rg] = *(const short8*)((const char*)lds_a + row*512 + ((dk*128 + s*64 + hi*16) ^ ((row&7)<<4)));
      }
      #pragma unroll
      for (int rg=0;rg<4;rg++)
        #pragma unroll
        for (int cf=0;cf<4;cf++)
          acc[rg][cf] = mfma16(af[rg], bf[cf], acc[rg][cf]);
    }
  }
  #pragma unroll
  for (int rg=0;rg<4;rg++)
    #pragma unroll
    for (int cf=0;cf<4;cf++){
      int col = w*64 + cf*16 + lo;
      float bs = bo[col];
      #pragma unroll
      for (int r=0;r<4;r++){
        size_t flat = (size_t)(row0 + rg*16 + hi*4 + r)*256 + col;
        out[flat] = x[flat] + acc[rg][cf][r] + bs;
      }
    }
}

// ---------------- kernel 4: split-K flash attention, 2-blocks/CU variant --------
// grid 512 x 256 thr (4 waves x 32 q-rows = 128-row q-tile), LDS 64KB
// single-buffered {K0,K1 @0/16K; V0,V1 @32K/48K} -> 2 blocks/CU: cross-block
// TLP hides stage/barrier drain (replaces the 1-block prefetch of r10-r19).
// Per-wave math/layouts byte-identical to the validated 106.5us kernel.
// bid: x=bid&7 (XCD), idx=bid>>3 in [0,64); combo=x*2+(idx&1); b=combo>>2,
// ks=combo&3; qt=idx>>1 in [0,32).
__global__ __launch_bounds__(256,2) void k_attn(const u16* q, const u16* k,
                                                const u16* vt, u16* part, float2* ml){
  __shared__ char smem[65536];
  const int t = threadIdx.x, w = t>>6, l = t&63;
  const int lq = l&31, h = l>>5;
  const int bid = blockIdx.x;
  const int x = bid&7, idx = bid>>3;
  const int combo = x*2 + (idx&1);
  const int b = combo>>2, ks = combo&3, qt = idx>>1;

  const char* kg = (const char*)k  + ((size_t)b*4096 + (size_t)ks*1024)*512;
  const char* vg = (const char*)vt + (size_t)b*2097152 + (size_t)ks*2048;

  // Q fragments: qf[dk]: Q[q = lq][d = dk*16 + h*8 + e]
  short8 qf[16];
  {
    const char* qrow = (const char*)q + ((size_t)b*4096 + qt*128 + w*32 + lq)*512;
    #pragma unroll
    for (int dk=0;dk<16;dk++) qf[dk] = *(const short8*)(qrow + dk*32 + h*16);
  }

  f32x16 O[8];
  #pragma unroll
  for (int ct=0;ct<8;ct++) O[ct] = z16();
  float m_run = -1e30f, l_run = 0.f;

  // 256 threads stage 64KB (2 subs x {16KB K + 16KB V}): 4+4 gl_lds per sub.
  auto stage = [&](int ti){
    #pragma unroll
    for (int sub=0; sub<2; ++sub){
      char* kd = smem + sub*16384;
      char* vd = smem + 32768 + sub*16384;
      #pragma unroll
      for (int j=0;j<4;j++){
        int key = w*8 + j*2 + h;                       // 0..31 within subtile
        gl_lds16(kg + (size_t)(ti*64 + sub*32 + key)*512 + (((l&31)*16) ^ ((key&7)<<4)),
                 kd + (w*4+j)*1024);
      }
      #pragma unroll
      for (int j=0;j<4;j++){
        int c = w*64 + j*16 + (l>>2);                  // 0..255
        gl_lds16(vg + (size_t)c*8192 + ti*128 + sub*64 + (((l&3)*16) ^ (((l>>3)&3)<<4)),
                 vd + (w*4+j)*1024);
      }
    }
  };

  // softmax + PV for one 32-key subtile from S (lane owns q=lq)
  auto smpv = [&](const f32x16& S, const char* vbuf){
    float pmax = S[0];
    #pragma unroll
    for (int r=1;r<16;r++) pmax = fmaxf(pmax, S[r]);
    pmax = fmaxf(pmax, __shfl_xor(pmax, 32, 64));
    if (__any(pmax > m_run + 8.f)){
      float mn = fmaxf(m_run, pmax);
      float sclq = exp2f(m_run - mn);
      m_run = mn;
      l_run *= sclq;
      #pragma unroll
      for (int r=0;r<16;r++){
        float sr = __shfl(sclq, (r&3)+8*(r>>2)+4*h, 64);   // scale for O-row crow(r,h)
        #pragma unroll
        for (int ct=0;ct<8;ct++) O[ct][r] *= sr;
      }
    }
    float p[16]; float ps = 0.f;
    #pragma unroll
    for (int r=0;r<16;r++){ p[r] = exp2f(S[r] - m_run); ps += p[r]; }
    l_run += ps + __shfl_xor(ps, 32, 64);
    u32 pk[8];
    #pragma unroll
    for (int j=0;j<8;j++){
      u32 u0 = __builtin_bit_cast(u32, p[2*j]);
      u32 u1 = __builtin_bit_cast(u32, p[2*j+1]);
      pk[j] = (u1 & 0xffff0000u) | (u0 >> 16);   // truncation to bf16 (P in [0,256])
    }
    #pragma unroll
    for (int kc=0;kc<2;kc++){
      u32 sA = h ? pk[4*kc]   : pk[4*kc+2];
      u32 sB = h ? pk[4*kc+1] : pk[4*kc+3];
      u32 xA = __shfl_xor(sA, 32, 64);
      u32 xB = __shfl_xor(sB, 32, 64);
      U8 pa;
      pa.u[0] = h ? xA : pk[4*kc];
      pa.u[1] = h ? xB : pk[4*kc+1];
      pa.u[2] = h ? pk[4*kc+2] : xA;
      pa.u[3] = h ? pk[4*kc+3] : xB;
      #pragma unroll
      for (int ct=0;ct<8;ct++){
        short8 vb = *(const short8*)(vbuf + (size_t)(ct*32+lq)*64 + ((kc*32 + h*16) ^ (((lq>>1)&3)<<4)));
        O[ct] = mfma32(pa.s, vb, O[ct]);
      }
    }
  };

  for (int tile=0; tile<16; ++tile){
    stage(tile);
    __syncthreads();           // staging landed (vmcnt drained by barrier)
    const char* kbuf0 = smem;
    const char* kbuf1 = smem + 16384;
    const char* vbuf0 = smem + 32768;
    const char* vbuf1 = smem + 49152;

    // ---- QK^T for BOTH subtiles: two independent 16-deep chains ----
    f32x16 S0 = z16(), S1 = z16();
    #pragma unroll
    for (int dk=0;dk<16;dk++){
      int dby = (dk*32 + h*16) ^ ((lq&7)<<4);
      short8 k0 = *(const short8*)(kbuf0 + (size_t)lq*512 + dby);
      short8 k1 = *(const short8*)(kbuf1 + (size_t)lq*512 + dby);
      S0 = mfma32(k0, qf[dk], S0);
      S1 = mfma32(k1, qf[dk], S1);
    }

    smpv(S0, vbuf0);
    smpv(S1, vbuf1);
    __syncthreads();           // all reads done before next tile's stage overwrites
  }

  // ---- epilogue: otile [128 q][256 c] bf16 = 64KB over whole smem ----
  if (h == 0)
    ml[(size_t)combo*4096 + qt*128 + w*32 + lq] = make_float2(m_run, l_run);
  u16* otile = (u16*)smem;
  #pragma unroll
  for (int ct=0;ct<8;ct++)
    #pragma unroll
    for (int r=0;r<16;r++){
      int row = w*32 + (r&3) + 8*(r>>2) + 4*h;
      otile[row*256 + ct*32 + lq] = f2bf(O[ct][r]);
    }
  __syncthreads();
  {
    const char* sb2 = (const char*)smem;
    char* gb2 = (char*)part + ((size_t)combo*4096 + (size_t)qt*128)*512;
    #pragma unroll
    for (int j=0;j<16;j++)
      *(uint4*)(gb2 + t*16 + (size_t)j*4096) = *(const uint4*)(sb2 + t*16 + (size_t)j*4096);
  }
}

// ---------------- kernel 4b: combine split-K partials -> h2t (b,c,n) ----------------
__global__ __launch_bounds__(256,2) void k_combine(const u16* part, const float2* ml, u16* h2t){
  __shared__ u16 tile[64*256];   // [n][c], XOR-swizzled
  const int t = threadIdx.x, b = blockIdx.y, n0 = blockIdx.x*64;
  const int n = t>>2, cc = (t&3)*64;
  const int gn = n0 + n;
  float2 st[4]; float ms = -1e30f;
  #pragma unroll
  for (int ksi=0;ksi<4;ksi++){ st[ksi] = ml[(size_t)(b*4+ksi)*4096 + gn]; ms = fmaxf(ms, st[ksi].x); }
  float wn[4]; float denom = 0.f;
  #pragma unroll
  for (int ksi=0;ksi<4;ksi++){ wn[ksi] = exp2f(st[ksi].x - ms); denom += wn[ksi]*st[ksi].y; }
  float inv = 1.f/denom;
  #pragma unroll
  for (int ksi=0;ksi<4;ksi++) wn[ksi] *= inv;
  float acc[64];
  #pragma unroll
  for (int j=0;j<64;j++) acc[j] = 0.f;
  #pragma unroll
  for (int ksi=0;ksi<4;ksi++){
    const u16* src = part + ((size_t)(b*4+ksi)*4096 + gn)*256 + cc;
    float wv = wn[ksi];
    #pragma unroll
    for (int j8=0;j8<8;j8++){
      short8 v = *(const short8*)(src + j8*8);
      #pragma unroll
      for (int e=0;e<8;e++){
        u32 uu = ((u32)(u16)v[e])<<16;
        acc[j8*8+e] += wv * __builtin_bit_cast(float, uu);
      }
    }
  }
  char* tb = (char*)tile;
  #pragma unroll
  for (int j=0;j<32;j++){
    u32 pkv = ((u32)f2bf(acc[2*j+1])<<16) | f2bf(acc[2*j]);
    *(u32*)(tb + n*512 + ((cc*2 + j*4) ^ ((n&7)<<4))) = pkv;
  }
  __syncthreads();
  {
    const char* tbc = (const char*)tile;
    u32 outw[32];
    #pragma unroll
    for (int j=0;j<32;j++){
      u16 v0 = *(const u16*)(tbc + (2*j  )*512 + ((t*2) ^ (((2*j  )&7)<<4)));
      u16 v1 = *(const u16*)(tbc + (2*j+1)*512 + ((t*2) ^ (((2*j+1)&7)<<4)));
      outw[j] = ((u32)v1<<16) | v0;
    }
    char* dst = (char*)h2t + ((size_t)(b*256 + t)*4096 + n0)*2;
    #pragma unroll
    for (int j=0;j<8;j++){
      uint4 vv; vv.x = outw[4*j]; vv.y = outw[4*j+1]; vv.z = outw[4*j+2]; vv.w = outw[4*j+3];
      *(uint4*)(dst + j*16) = vv;
    }
  }
}

// ---------------- launch ----------------
extern "C" void kernel_launch(void* const* d_in, const int* in_sizes, int n_in,
                              void* d_out, int out_size, void* d_ws, size_t ws_size,
                              hipStream_t stream) {
  const float* x    = (const float*)d_in[0];
  const float* gn_w = (const float*)d_in[1];
  const float* gn_b = (const float*)d_in[2];
  const float* wq   = (const float*)d_in[3];
  const float* bq   = (const float*)d_in[4];
  const float* wk   = (const float*)d_in[5];
  const float* bk   = (const float*)d_in[6];
  const float* wv   = (const float*)d_in[7];
  const float* bv   = (const float*)d_in[8];
  const float* wo   = (const float*)d_in[9];
  const float* bo   = (const float*)d_in[10];
  float* out = (float*)d_out;
  char* ws = (char*)d_ws;

  u16*    wbf   = (u16*)(ws + OFF_WBF);
  float2* stats = (float2*)(ws + OFF_STATS);
  u16*    qb    = (u16*)(ws + OFF_Q);
  u16*    kb    = (u16*)(ws + OFF_K);
  u16*    vt    = (u16*)(ws + OFF_VT);
  u16*    h2t   = (u16*)(ws + OFF_H2T);
  u16*    part  = (u16*)(ws + OFF_PART);
  float2* ml    = (float2*)(ws + OFF_ML);

  k_prepstats<<<768,        256, 0, stream>>>(wq, wk, wv, wo, wbf, x, stats);
  k_qkv      <<<256,        256, 0, stream>>>(x, gn_w, gn_b, stats, wbf, bq, bk, bv, qb, kb, vt);
  k_attn     <<<512,        256, 0, stream>>>(qb, kb, vt, part, ml);
  k_combine  <<<dim3(64,4), 256, 0, stream>>>(part, ml, h2t);
  k_out      <<<256,        256, 0, stream>>>(h2t, wbf + 3*65536, bo, x, out);
}

// Round 21
// 161.454 us; speedup vs baseline: 1.0152x; 1.0152x over previous
//
#include <hip/hip_runtime.h>

typedef unsigned short u16;
typedef unsigned int   u32;
typedef __attribute__((ext_vector_type(8)))  short short8;   // 8 x bf16 (raw bits)
typedef __attribute__((ext_vector_type(4)))  float f32x4;
typedef __attribute__((ext_vector_type(16))) float f32x16;

#define DI __device__ __forceinline__

DI u16 f2bf(float f){
  u32 u = __builtin_bit_cast(u32, f);
  u += 0x7fffu + ((u >> 16) & 1u);          // round-to-nearest-even
  return (u16)(u >> 16);
}

DI void gl_lds16(const void* g, void* l){
  __builtin_amdgcn_global_load_lds((const __attribute__((address_space(1))) void*)g,
                                   (__attribute__((address_space(3))) void*)l, 16, 0, 0);
}

DI f32x4 mfma16(short8 a, short8 b, f32x4 c){
  return __builtin_amdgcn_mfma_f32_16x16x32_bf16(a, b, c, 0, 0, 0);
}
DI f32x16 mfma32(short8 a, short8 b, f32x16 c){
  return __builtin_amdgcn_mfma_f32_32x32x16_bf16(a, b, c, 0, 0, 0);
}
DI f32x16 z16(){
  f32x16 v;
  #pragma unroll
  for (int i=0;i<16;i++) v[i]=0.f;
  return v;
}

union U8 { u32 u[4]; short8 s; };

// ---------------- workspace layout (bytes) ----------------
#define OFF_WBF   0u
#define OFF_STATS (512u<<10)
#define OFF_Q     ((1u<<20) + (8u<<20))
#define OFF_K     ((1u<<20) + (16u<<20))
#define OFF_VT    ((1u<<20) + (24u<<20))
#define OFF_H2T   OFF_Q                     // alias: q dead before k_combine writes h2t
#define OFF_PART  ((1u<<20) + (32u<<20))    // 16 combos x (4096,256) bf16 = 32 MB
#define OFF_ML    ((1u<<20) + (96u<<20))    // 16 combos x 4096 float2 = 512 KB

// ------- kernel 0+1 merged: weight bf16 prep (blocks 0..255) + gn stats (256..767) -------
__global__ void k_prepstats(const float* wq, const float* wk, const float* wv, const float* wo,
                            u16* wbf, const float* x, float2* stats){
  const int bid = blockIdx.x;
  if (bid < 256){
    const int wi = bid >> 6;                  // 0..3
    const float* src = (wi==0)?wq:(wi==1)?wk:(wi==2)?wv:wo;
    u16* d = wbf + wi*65536;
    int i = ((bid&63)*256 + threadIdx.x)*4;
    float4 v = *(const float4*)(src + i);
    u32 lo = (u32)f2bf(v.x) | ((u32)f2bf(v.y)<<16);
    u32 hi = (u32)f2bf(v.z) | ((u32)f2bf(v.w)<<16);
    *(uint2*)(d + i) = make_uint2(lo, hi);
    return;
  }
  const int bg = bid - 256;                    // 0..511: b*128 + g
  const float* p = x + (size_t)bg*8192;
  float s = 0.f, ss = 0.f;
  #pragma unroll
  for (int i=0;i<8;i++){
    float4 v = *(const float4*)(p + threadIdx.x*4 + i*1024);
    s  += v.x+v.y+v.z+v.w;
    ss += v.x*v.x + v.y*v.y + v.z*v.z + v.w*v.w;
  }
  #pragma unroll
  for (int off=1; off<64; off<<=1){ s += __shfl_xor(s, off, 64); ss += __shfl_xor(ss, off, 64); }
  __shared__ float as[4], aq[4];
  int w = threadIdx.x>>6;
  if ((threadIdx.x&63)==0){ as[w]=s; aq[w]=ss; }
  __syncthreads();
  if (threadIdx.x==0){
    s = as[0]+as[1]+as[2]+as[3]; ss = aq[0]+aq[1]+aq[2]+aq[3];
    float mu = s * (1.f/8192.f);
    float var = ss * (1.f/8192.f) - mu*mu;
    stats[bg] = make_float2(mu, rsqrtf(var + 1e-5f));
  }
}

// ---------------- kernel 3: fused GroupNorm + QKV projections ----------------
// grid 256 x 256 thr: block = 64 tokens. Phase 0 normalizes x directly into
// lds_a in GEMM-A layout (validated round 17).
__global__ __launch_bounds__(256,2) void k_qkv(const float* x, const float* gw,
    const float* gb, const float2* stats, const u16* wbf,
    const float* bq, const float* bk, const float* bv,
    u16* qo, u16* ko, u16* vt){
  __shared__ u16 lds_a[64*256];    // 32KB
  const int t = threadIdx.x, row0 = blockIdx.x*64;
  const int w = t>>6, l = t&63, lo = l&15, hi = l>>4;
  // ---- phase 0: normalize 64-token x tile straight into lds_a ----
  {
    const int b = row0>>12, n0 = row0&4095;
    const float* xb = x + (size_t)b*1048576;
    #pragma unroll
    for (int p=0;p<4;p++){
      int c = p*64 + (t>>2);
      float2 st = stats[b*128 + (c>>1)];
      float scl = st.y * gw[c];
      float off = gb[c] - st.x*scl;
      const float* src = xb + (size_t)c*4096 + n0 + (t&3)*16;
      #pragma unroll
      for (int u2=0;u2<4;u2++){
        float4 v = *(const float4*)(src + u2*4);
        float vv[4] = {v.x,v.y,v.z,v.w};
        #pragma unroll
        for (int j=0;j<4;j++){
          int n = (t&3)*16 + u2*4 + j;
          int addr = n*512 + ((c*2) ^ ((n&7)<<4));
          *(u16*)((char*)lds_a + addr) = f2bf(vv[j]*scl + off);
        }
      }
    }
    __syncthreads();
  }
  auto compute = [&](const u16* W, f32x4 acc[4][4]){
    #pragma unroll
    for (int i=0;i<4;i++)
      #pragma unroll
      for (int j=0;j<4;j++) acc[i][j] = (f32x4){0.f,0.f,0.f,0.f};
    const char* Wb = (const char*)W;
    #pragma unroll
    for (int dk=0; dk<4; dk++){
      #pragma unroll
      for (int s=0;s<2;s++){
        short8 af[4], bf[4];
        #pragma unroll
        for (int cf=0;cf<4;cf++){
          int col = w*64 + cf*16 + lo;
          bf[cf] = *(const short8*)(Wb + (size_t)col*512 + dk*128 + s*64 + hi*16);
        }
        #pragma unroll
        for (int rg=0;rg<4;rg++){
          int row = rg*16 + lo;
          af[rg] = *(const short8*)((const char*)lds_a + row*512 + ((dk*128 + s*64 + hi*16) ^ ((row&7)<<4)));
        }
        #pragma unroll
        for (int rg=0;rg<4;rg++)
          #pragma unroll
          for (int cf=0;cf<4;cf++)
            acc[rg][cf] = mfma16(af[rg], bf[cf], acc[rg][cf]);
      }
    }
  };
  f32x4 acc[4][4];
  compute(wbf, acc);
  #pragma unroll
  for (int rg=0;rg<4;rg++)
    #pragma unroll
    for (int cf=0;cf<4;cf++){
      int col = w*64 + cf*16 + lo;
      float bs = bq[col];
      #pragma unroll
      for (int r=0;r<4;r++){
        int grow = row0 + rg*16 + hi*4 + r;
        qo[(size_t)grow*256 + col] = f2bf((acc[rg][cf][r] + bs)*0.09016844f);
      }
    }
  compute(wbf + 65536, acc);
  #pragma unroll
  for (int rg=0;rg<4;rg++)
    #pragma unroll
    for (int cf=0;cf<4;cf++){
      int col = w*64 + cf*16 + lo;
      float bs = bk[col];
      #pragma unroll
      for (int r=0;r<4;r++){
        int grow = row0 + rg*16 + hi*4 + r;
        ko[(size_t)grow*256 + col] = f2bf(acc[rg][cf][r] + bs);
      }
    }
  compute(wbf + 2*65536, acc);
  __syncthreads();
  #pragma unroll
  for (int rg=0;rg<4;rg++)
    #pragma unroll
    for (int cf=0;cf<4;cf++){
      int col = w*64 + cf*16 + lo;
      float bs = bv[col];
      ushort4 pk;
      pk.x = f2bf(acc[rg][cf][0]+bs); pk.y = f2bf(acc[rg][cf][1]+bs);
      pk.z = f2bf(acc[rg][cf][2]+bs); pk.w = f2bf(acc[rg][cf][3]+bs);
      int rl = rg*16 + hi*4;
      int addr = col*128 + ((rl*2) ^ ((col&7)<<4));     // lds_a reused: [256 c][64 rows]
      *(ushort4*)((char*)lds_a + addr) = pk;
    }
  __syncthreads();
  {
    int b = row0 >> 12, nb = row0 & 4095;
    #pragma unroll
    for (int p=0;p<8;p++){
      int c = p*32 + (t>>3), i = t&7;
      uint4 vd = *(const uint4*)((const char*)lds_a + c*128 + ((i*16) ^ ((c&7)<<4)));
      *(uint4*)((char*)vt + ((size_t)(b*256 + c)*4096 + nb)*2 + i*16) = vd;
    }
  }
}

// ---------------- kernel 5: output projection + residual ----------------
__global__ __launch_bounds__(256,2) void k_out(const u16* h2t, const u16* wo,
    const float* bo, const float* x, float* out){
  __shared__ u16 lds_a[64*256];
  const int t = threadIdx.x, row0 = blockIdx.x*64;
  const int w = t>>6, l = t&63, lo = l&15, hi = l>>4;
  {
    const char* Ab = (const char*)h2t + (size_t)row0*512;
    #pragma unroll
    for (int i=0;i<8;i++){
      int row = w*16 + i*2 + (l>>5);
      gl_lds16(Ab + row*512 + (((l&31)*16) ^ ((row&7)<<4)), lds_a + w*4096 + i*512);
    }
    __syncthreads();
  }
  f32x4 acc[4][4];
  #pragma unroll
  for (int i=0;i<4;i++)
    #pragma unroll
    for (int j=0;j<4;j++) acc[i][j] = (f32x4){0.f,0.f,0.f,0.f};
  const char* Wb = (const char*)wo;
  #pragma unroll
  for (int dk=0; dk<4; dk++){
    #pragma unroll
    for (int s=0;s<2;s++){
      short8 af[4], bf[4];
      #pragma unroll
      for (int cf=0;cf<4;cf++){
        int col = w*64 + cf*16 + lo;
        bf[cf] = *(const short8*)(Wb + (size_t)col*512 + dk*128 + s*64 + hi*16);
      }
      #pragma unroll
      for (int rg=0;rg<4;rg++){
        int row = rg*16 + lo;
        af[rg] = *(const short8*)((const char*)lds_a + row*512 + ((dk*128 + s*64 + hi*16) ^ ((row&7)<<4)));
      }
      #pragma unroll
      for (int rg=0;rg<4;rg++)
        #pragma unroll
        for (int cf=0;cf<4;cf++)
          acc[rg][cf] = mfma16(af[rg], bf[cf], acc[rg][cf]);
    }
  }
  #pragma unroll
  for (int rg=0;rg<4;rg++)
    #pragma unroll
    for (int cf=0;cf<4;cf++){
      int col = w*64 + cf*16 + lo;
      float bs = bo[col];
      #pragma unroll
      for (int r=0;r<4;r++){
        size_t flat = (size_t)(row0 + rg*16 + hi*4 + r)*256 + col;
        out[flat] = x[flat] + acc[rg][cf][r] + bs;
      }
    }
}

// ---------------- kernel 4: split-K flash attention (round-19 best, 106.5us) ----
__global__ __launch_bounds__(512,2) void k_attn(const u16* q, const u16* k,
                                                const u16* vt, u16* part, float2* ml){
  __shared__ char smem[131072];  // K: buf*32768+sub*16384 ; V: 65536 + same
  const int t = threadIdx.x, w = t>>6, l = t&63;
  const int lq = l&31, h = l>>5;
  const int bid = blockIdx.x;
  const int x = bid&7, idx = bid>>3;
  const int combo = x*2 + (idx&1);
  const int b = combo>>2, ks = combo&3, qt = idx>>1;

  const char* kg = (const char*)k  + ((size_t)b*4096 + (size_t)ks*1024)*512;
  const char* vg = (const char*)vt + (size_t)b*2097152 + (size_t)ks*2048;

  // Q fragments: qf[dk]: Q[q = lq][d = dk*16 + h*8 + e]
  short8 qf[16];
  {
    const char* qrow = (const char*)q + ((size_t)b*4096 + qt*256 + w*32 + lq)*512;
    #pragma unroll
    for (int dk=0;dk<16;dk++) qf[dk] = *(const short8*)(qrow + dk*32 + h*16);
  }

  f32x16 O[8];
  #pragma unroll
  for (int ct=0;ct<8;ct++) O[ct] = z16();
  float m_run = -1e30f, l_run = 0.f;

  // 512 threads stage 64KB: per sub (32 keys): 16KB K + 16KB V, 2+2 gl_lds each.
  auto stage = [&](int ti, int buf){
    #pragma unroll
    for (int sub=0; sub<2; ++sub){
      char* kd = smem + buf*32768 + sub*16384;
      char* vd = smem + 65536 + buf*32768 + sub*16384;
      #pragma unroll
      for (int j=0;j<2;j++){
        int key = w*4 + j*2 + h;                       // 0..31 within subtile
        gl_lds16(kg + (size_t)(ti*64 + sub*32 + key)*512 + (((l&31)*16) ^ ((key&7)<<4)),
                 kd + (w*2+j)*1024);
      }
      #pragma unroll
      for (int j=0;j<2;j++){
        int c = w*32 + j*16 + (l>>2);                  // 0..255
        gl_lds16(vg + (size_t)c*8192 + ti*128 + sub*64 + (((l&3)*16) ^ (((l>>3)&3)<<4)),
                 vd + (w*2+j)*1024);
      }
    }
  };

  // softmax + PV for one 32-key subtile from S (lane owns q=lq)
  auto smpv = [&](const f32x16& S, const char* vbuf){
    float pmax = S[0];
    #pragma unroll
    for (int r=1;r<16;r++) pmax = fmaxf(pmax, S[r]);
    pmax = fmaxf(pmax, __shfl_xor(pmax, 32, 64));
    if (__any(pmax > m_run + 8.f)){
      float mn = fmaxf(m_run, pmax);
      float sclq = exp2f(m_run - mn);
      m_run = mn;
      l_run *= sclq;
      #pragma unroll
      for (int r=0;r<16;r++){
        float sr = __shfl(sclq, (r&3)+8*(r>>2)+4*h, 64);   // scale for O-row crow(r,h)
        #pragma unroll
        for (int ct=0;ct<8;ct++) O[ct][r] *= sr;
      }
    }
    float p[16]; float ps = 0.f;
    #pragma unroll
    for (int r=0;r<16;r++){ p[r] = exp2f(S[r] - m_run); ps += p[r]; }
    l_run += ps + __shfl_xor(ps, 32, 64);
    u32 pk[8];
    #pragma unroll
    for (int j=0;j<8;j++){
      u32 u0 = __builtin_bit_cast(u32, p[2*j]);
      u32 u1 = __builtin_bit_cast(u32, p[2*j+1]);
      pk[j] = (u1 & 0xffff0000u) | (u0 >> 16);   // truncation to bf16 (P in [0,256])
    }
    #pragma unroll
    for (int kc=0;kc<2;kc++){
      u32 sA = h ? pk[4*kc]   : pk[4*kc+2];
      u32 sB = h ? pk[4*kc+1] : pk[4*kc+3];
      u32 xA = __shfl_xor(sA, 32, 64);
      u32 xB = __shfl_xor(sB, 32, 64);
      U8 pa;
      pa.u[0] = h ? xA : pk[4*kc];
      pa.u[1] = h ? xB : pk[4*kc+1];
      pa.u[2] = h ? pk[4*kc+2] : xA;
      pa.u[3] = h ? pk[4*kc+3] : xB;
      #pragma unroll
      for (int ct=0;ct<8;ct++){
        short8 vb = *(const short8*)(vbuf + (size_t)(ct*32+lq)*64 + ((kc*32 + h*16) ^ (((lq>>1)&3)<<4)));
        O[ct] = mfma32(pa.s, vb, O[ct]);
      }
    }
  };

  stage(0, 0);
  __syncthreads();

  for (int tile=0; tile<16; ++tile){
    const int cur = tile&1;
    if (tile < 15) stage(tile+1, cur^1);
    const char* kbuf0 = smem + cur*32768;
    const char* kbuf1 = kbuf0 + 16384;
    const char* vbuf0 = smem + 65536 + cur*32768;
    const char* vbuf1 = vbuf0 + 16384;

    // ---- QK^T for BOTH subtiles: two independent 16-deep chains ----
    f32x16 S0 = z16(), S1 = z16();
    #pragma unroll
    for (int dk=0;dk<16;dk++){
      int dby = (dk*32 + h*16) ^ ((lq&7)<<4);
      short8 k0 = *(const short8*)(kbuf0 + (size_t)lq*512 + dby);
      short8 k1 = *(const short8*)(kbuf1 + (size_t)lq*512 + dby);
      S0 = mfma32(k0, qf[dk], S0);
      S1 = mfma32(k1, qf[dk], S1);
    }

    smpv(S0, vbuf0);
    smpv(S1, vbuf1);
    __syncthreads();
  }

  // ---- epilogue ----
  if (h == 0)
    ml[(size_t)combo*4096 + qt*256 + w*32 + lq] = make_float2(m_run, l_run);
  // two rounds: waves 0-3 then 4-7 dump their 128 q-rows through smem to global.
  u16* otile = (u16*)smem;
  char* pbase = (char*)part + ((size_t)combo*4096 + (size_t)qt*256)*512;
  #pragma unroll
  for (int rd=0; rd<2; ++rd){
    __syncthreads();
    if ((w>>2) == rd){
      int wl = w&3;
      #pragma unroll
      for (int ct=0;ct<8;ct++)
        #pragma unroll
        for (int r=0;r<16;r++){
          int row = wl*32 + (r&3) + 8*(r>>2) + 4*h;
          otile[row*256 + ct*32 + lq] = f2bf(O[ct][r]);
        }
    }
    __syncthreads();
    const char* sb2 = (const char*)smem;
    char* gb2 = pbase + (size_t)rd*65536;
    #pragma unroll
    for (int j=0;j<8;j++)
      *(uint4*)(gb2 + t*16 + (size_t)j*8192) = *(const uint4*)(sb2 + t*16 + (size_t)j*8192);
  }
}

// ---------------- kernel 4b: combine split-K partials -> h2t (b,c,n) ----------------
__global__ __launch_bounds__(256,2) void k_combine(const u16* part, const float2* ml, u16* h2t){
  __shared__ u16 tile[64*256];   // [n][c], XOR-swizzled
  const int t = threadIdx.x, b = blockIdx.y, n0 = blockIdx.x*64;
  const int n = t>>2, cc = (t&3)*64;
  const int gn = n0 + n;
  float2 st[4]; float ms = -1e30f;
  #pragma unroll
  for (int ksi=0;ksi<4;ksi++){ st[ksi] = ml[(size_t)(b*4+ksi)*4096 + gn]; ms = fmaxf(ms, st[ksi].x); }
  float wn[4]; float denom = 0.f;
  #pragma unroll
  for (int ksi=0;ksi<4;ksi++){ wn[ksi] = exp2f(st[ksi].x - ms); denom += wn[ksi]*st[ksi].y; }
  float inv = 1.f/denom;
  #pragma unroll
  for (int ksi=0;ksi<4;ksi++) wn[ksi] *= inv;
  float acc[64];
  #pragma unroll
  for (int j=0;j<64;j++) acc[j] = 0.f;
  #pragma unroll
  for (int ksi=0;ksi<4;ksi++){
    const u16* src = part + ((size_t)(b*4+ksi)*4096 + gn)*256 + cc;
    float wv = wn[ksi];
    #pragma unroll
    for (int j8=0;j8<8;j8++){
      short8 v = *(const short8*)(src + j8*8);
      #pragma unroll
      for (int e=0;e<8;e++){
        u32 uu = ((u32)(u16)v[e])<<16;
        acc[j8*8+e] += wv * __builtin_bit_cast(float, uu);
      }
    }
  }
  char* tb = (char*)tile;
  #pragma unroll
  for (int j=0;j<32;j++){
    u32 pkv = ((u32)f2bf(acc[2*j+1])<<16) | f2bf(acc[2*j]);
    *(u32*)(tb + n*512 + ((cc*2 + j*4) ^ ((n&7)<<4))) = pkv;
  }
  __syncthreads();
  {
    const char* tbc = (const char*)tile;
    u32 outw[32];
    #pragma unroll
    for (int j=0;j<32;j++){
      u16 v0 = *(const u16*)(tbc + (2*j  )*512 + ((t*2) ^ (((2*j  )&7)<<4)));
      u16 v1 = *(const u16*)(tbc + (2*j+1)*512 + ((t*2) ^ (((2*j+1)&7)<<4)));
      outw[j] = ((u32)v1<<16) | v0;
    }
    char* dst = (char*)h2t + ((size_t)(b*256 + t)*4096 + n0)*2;
    #pragma unroll
    for (int j=0;j<8;j++){
      uint4 vv; vv.x = outw[4*j]; vv.y = outw[4*j+1]; vv.z = outw[4*j+2]; vv.w = outw[4*j+3];
      *(uint4*)(dst + j*16) = vv;
    }
  }
}

// ---------------- launch ----------------
extern "C" void kernel_launch(void* const* d_in, const int* in_sizes, int n_in,
                              void* d_out, int out_size, void* d_ws, size_t ws_size,
                              hipStream_t stream) {
  const float* x    = (const float*)d_in[0];
  const float* gn_w = (const float*)d_in[1];
  const float* gn_b = (const float*)d_in[2];
  const float* wq   = (const float*)d_in[3];
  const float* bq   = (const float*)d_in[4];
  const float* wk   = (const float*)d_in[5];
  const float* bk   = (const float*)d_in[6];
  const float* wv   = (const float*)d_in[7];
  const float* bv   = (const float*)d_in[8];
  const float* wo   = (const float*)d_in[9];
  const float* bo   = (const float*)d_in[10];
  float* out = (float*)d_out;
  char* ws = (char*)d_ws;

  u16*    wbf   = (u16*)(ws + OFF_WBF);
  float2* stats = (float2*)(ws + OFF_STATS);
  u16*    qb    = (u16*)(ws + OFF_Q);
  u16*    kb    = (u16*)(ws + OFF_K);
  u16*    vt    = (u16*)(ws + OFF_VT);
  u16*    h2t   = (u16*)(ws + OFF_H2T);
  u16*    part  = (u16*)(ws + OFF_PART);
  float2* ml    = (float2*)(ws + OFF_ML);

  k_prepstats<<<768,        256, 0, stream>>>(wq, wk, wv, wo, wbf, x, stats);
  k_qkv      <<<256,        256, 0, stream>>>(x, gn_w, gn_b, stats, wbf, bq, bk, bv, qb, kb, vt);
  k_attn     <<<256,        512, 0, stream>>>(qb, kb, vt, part, ml);
  k_combine  <<<dim3(64,4), 256, 0, stream>>>(part, ml, h2t);
  k_out      <<<256,        256, 0, stream>>>(h2t, wbf + 3*65536, bo, x, out);
}